// Round 2
// baseline (244.066 us; speedup 1.0000x reference)
//
#include <hip/hip_runtime.h>
#include <hip/hip_bf16.h>
#include <stdint.h>

// GAT layer: N=8192, F_IN=256, F_OUT=64, two branches (adj_in/adj_out), shared 'a'.
// out = elu(0.5*(softmax_masked(LR(h_in a_src + (h_in a_dst)^T), adj_in) @ h_in
//            + softmax_masked(...out...) @ h_out))

#define NN 8192
#define ALPHA 0.2f
#define L2E 1.44269504088896f
#define AL2E 0.288539008177792f   // 0.2 * log2(e)

typedef _Float16 f16;
typedef _Float16 f16x4 __attribute__((ext_vector_type(4)));
typedef _Float16 f16x8 __attribute__((ext_vector_type(8)));
typedef float f32x4 __attribute__((ext_vector_type(4)));

// workspace layout (bytes)
#define WS_WT    0u         // f16 [128][256]  (transposed W_in|W_out)
#define WS_HT    65536u     // f16 [2][64][8192] (h transposed, per branch)
#define WS_SRC   2162688u   // f32 [2][8192]
#define WS_DST   2228224u   // f32 [2][8192]
#define WS_DMAX  2293760u   // f32 [2]
#define WS_PACC  2294016u   // f32 [2][8192][64]

// ---------------- kernel 1: WT[c][k] = W[k][c] as f16 ----------------
__global__ __launch_bounds__(256) void k1_wt(const float* __restrict__ Win,
                                             const float* __restrict__ Wout,
                                             f16* __restrict__ WT) {
    int c = blockIdx.x;          // 0..127 combined col
    int k = threadIdx.x;         // 0..255
    const float* W = (c < 64) ? Win : Wout;
    int cc = c & 63;
    WT[(size_t)c * 256 + k] = (f16)W[(size_t)k * 64 + cc];
}

// ---------------- kernel 2: h = x@W (MFMA), emit HT f16 + src/dst ----------------
__global__ __launch_bounds__(64) void k2_h(const float* __restrict__ x,
                                           const f16* __restrict__ WT,
                                           const float* __restrict__ a,
                                           f16* __restrict__ HT,
                                           float* __restrict__ srcw,
                                           float* __restrict__ dstw) {
    int l = threadIdx.x;
    int l15 = l & 15, lhi = l >> 4;
    int row0 = blockIdx.x * 16;

    f32x4 acc[8];
#pragma unroll
    for (int n = 0; n < 8; n++) { acc[n][0]=0.f; acc[n][1]=0.f; acc[n][2]=0.f; acc[n][3]=0.f; }

#pragma unroll
    for (int kc = 0; kc < 8; kc++) {
        int k = kc * 32 + lhi * 8;
        const float* xp = x + (size_t)(row0 + l15) * 256 + k;
        float4 xa = *(const float4*)xp;
        float4 xb = *(const float4*)(xp + 4);
        f16x8 af;
        af[0]=(f16)xa.x; af[1]=(f16)xa.y; af[2]=(f16)xa.z; af[3]=(f16)xa.w;
        af[4]=(f16)xb.x; af[5]=(f16)xb.y; af[6]=(f16)xb.z; af[7]=(f16)xb.w;
#pragma unroll
        for (int n = 0; n < 8; n++) {
            f16x8 bf = *(const f16x8*)(WT + (size_t)(16 * n + l15) * 256 + k);
            acc[n] = __builtin_amdgcn_mfma_f32_16x16x32_f16(af, bf, acc[n], 0, 0, 0);
        }
    }

    float as4[4], ad4[4];
#pragma unroll
    for (int nn = 0; nn < 4; nn++) {
        as4[nn] = a[16 * nn + l15];
        ad4[nn] = a[64 + 16 * nn + l15];
    }

    float s_in[4] = {0,0,0,0}, d_in[4] = {0,0,0,0};
    float s_out[4] = {0,0,0,0}, d_out[4] = {0,0,0,0};

#pragma unroll
    for (int n = 0; n < 8; n++) {
        int b = n >> 2;
        int ci = 16 * (n & 3) + l15;
        f16x4 hv;
#pragma unroll
        for (int q = 0; q < 4; q++) hv[q] = (f16)acc[n][q];
        *(f16x4*)(HT + (size_t)b * 524288 + (size_t)ci * 8192 + row0 + 4 * lhi) = hv;
#pragma unroll
        for (int q = 0; q < 4; q++) {
            float v = acc[n][q];
            if (b == 0) { s_in[q]  += v * as4[n & 3]; d_in[q]  += v * ad4[n & 3]; }
            else        { s_out[q] += v * as4[n & 3]; d_out[q] += v * ad4[n & 3]; }
        }
    }

#pragma unroll
    for (int q = 0; q < 4; q++) {
#pragma unroll
        for (int m = 1; m < 16; m <<= 1) {
            s_in[q]  += __shfl_xor(s_in[q],  m, 64);
            d_in[q]  += __shfl_xor(d_in[q],  m, 64);
            s_out[q] += __shfl_xor(s_out[q], m, 64);
            d_out[q] += __shfl_xor(d_out[q], m, 64);
        }
    }
    if (l15 == 0) {
        int row = row0 + 4 * lhi;
#pragma unroll
        for (int q = 0; q < 4; q++) {
            srcw[row + q]        = s_in[q];
            srcw[8192 + row + q] = s_out[q];
            dstw[row + q]        = d_in[q];
            dstw[8192 + row + q] = d_out[q];
        }
    }
}

// ---------------- kernel 3: per-branch max of dst ----------------
__global__ __launch_bounds__(256) void k3_dmax(const float* __restrict__ dstw,
                                               float* __restrict__ dmax) {
    __shared__ float red[2][4];
    int t = threadIdx.x;
    int l = t & 63, w = t >> 6;
    for (int b = 0; b < 2; b++) {
        float v = -1e30f;
        for (int i = t; i < 8192; i += 256) v = fmaxf(v, dstw[b * 8192 + i]);
#pragma unroll
        for (int m = 1; m < 64; m <<= 1) v = fmaxf(v, __shfl_xor(v, m, 64));
        if (l == 0) red[b][w] = v;
    }
    __syncthreads();
    if (t == 0) dmax[0] = fmaxf(fmaxf(red[0][0], red[0][1]), fmaxf(red[0][2], red[0][3]));
    if (t == 1) dmax[1] = fmaxf(fmaxf(red[1][0], red[1][1]), fmaxf(red[1][2], red[1][3]));
}

// ---------------- kernel 4: fused masked-softmax-attention ----------------
// Block = 4 waves, 16 rows, one branch. Wave wv owns j in [wv*2048, wv*2048+2048).
// No LDS in the main loop; B-fragments come straight from L2-resident HT.
// Partial acc + denominator merged across the 4 waves in LDS at the end.
__global__ __launch_bounds__(256, 4) void k4_main(const int* __restrict__ adj_in,
                                                  const int* __restrict__ adj_out,
                                                  const f16* __restrict__ HT,
                                                  const float* __restrict__ srcw,
                                                  const float* __restrict__ dstw,
                                                  const float* __restrict__ dmaxp,
                                                  float* __restrict__ pacc) {
    __shared__ float accL[4][16][64];   // 16 KB: per-wave partial out-tile
    __shared__ float dnp[4][16];
    __shared__ float dnr[16];

    int t = threadIdx.x;
    int branch = blockIdx.x & 1;
    int row0 = (blockIdx.x >> 1) * 16;
    const int* adj = branch ? adj_out : adj_in;
    const f16* htg = HT + (size_t)branch * 524288;
    const float* srcb = srcw + branch * 8192;
    const float* dstb = dstw + branch * 8192;
    float dmaxv = dmaxp[branch];

    int l = t & 63, wv = t >> 6;
    int l15 = l & 15, lhi = l >> 4, kslc = lhi * 8;

    // per-row softmax shift: mlog = LR(src + max_dst) * log2e (upper bound => exp <= 1)
    float srcv = srcb[row0 + l15];
    float md = srcv + dmaxv;
    float mlog = fmaxf(md, ALPHA * md) * L2E;
    float c1 = srcv * L2E - mlog;           // u = c1 + d*L2E
    float c2 = ALPHA * srcv * L2E - mlog;   // v = c2 + d*0.2*L2E

    int jbase = wv * 2048 + kslc;
    const int*   arow = adj  + (size_t)(row0 + l15) * 8192 + jbase;
    const float* drow = dstb + jbase;
    const f16*   hrow = htg  + (size_t)l15 * 8192 + jbase;

    f32x4 acc[4];
#pragma unroll
    for (int n = 0; n < 4; n++) { acc[n][0]=0.f; acc[n][1]=0.f; acc[n][2]=0.f; acc[n][3]=0.f; }
    float dn = 0.f;

    // prologue: load step 0
    int4   aC0 = *(const int4*)(arow);
    int4   aC1 = *(const int4*)(arow + 4);
    float4 dC0 = *(const float4*)(drow);
    float4 dC1 = *(const float4*)(drow + 4);
    f16x8  bC0 = *(const f16x8*)(hrow);
    f16x8  bC1 = *(const f16x8*)(hrow + 16 * 8192);
    f16x8  bC2 = *(const f16x8*)(hrow + 32 * 8192);
    f16x8  bC3 = *(const f16x8*)(hrow + 48 * 8192);

    for (int s = 0; s < 64; s++) {
        int off = ((s < 63) ? (s + 1) : s) * 32;
        // prefetch next step (adj from HBM, dst + HT from L2)
        int4   aN0 = *(const int4*)(arow + off);
        int4   aN1 = *(const int4*)(arow + off + 4);
        float4 dN0 = *(const float4*)(drow + off);
        float4 dN1 = *(const float4*)(drow + off + 4);
        f16x8  bN0 = *(const f16x8*)(hrow + off);
        f16x8  bN1 = *(const f16x8*)(hrow + off + 16 * 8192);
        f16x8  bN2 = *(const f16x8*)(hrow + off + 32 * 8192);
        f16x8  bN3 = *(const f16x8*)(hrow + off + 48 * 8192);

        // A-frag: masked exp weights for row l15, j-slice kslc..kslc+7
        f16x8 af;
#pragma unroll
        for (int e = 0; e < 8; e++) {
            int   av = (e < 4) ? ((const int*)&aC0)[e]   : ((const int*)&aC1)[e - 4];
            float d  = (e < 4) ? ((const float*)&dC0)[e] : ((const float*)&dC1)[e - 4];
            float u = fmaf(L2E, d, c1);
            float v = fmaf(AL2E, d, c2);
            float ev = exp2f(fmaxf(u, v));
            ev = (av > 0) ? ev : 0.f;
            dn += ev;
            af[e] = (f16)ev;
        }

        acc[0] = __builtin_amdgcn_mfma_f32_16x16x32_f16(af, bC0, acc[0], 0, 0, 0);
        acc[1] = __builtin_amdgcn_mfma_f32_16x16x32_f16(af, bC1, acc[1], 0, 0, 0);
        acc[2] = __builtin_amdgcn_mfma_f32_16x16x32_f16(af, bC2, acc[2], 0, 0, 0);
        acc[3] = __builtin_amdgcn_mfma_f32_16x16x32_f16(af, bC3, acc[3], 0, 0, 0);

        aC0 = aN0; aC1 = aN1; dC0 = dN0; dC1 = dN1;
        bC0 = bN0; bC1 = bN1; bC2 = bN2; bC3 = bN3;
    }

    // denominator: sum across lhi groups (same row l15) within wave
    dn += __shfl_xor(dn, 16, 64);
    dn += __shfl_xor(dn, 32, 64);
    if (lhi == 0) dnp[wv][l15] = dn;

    // stash per-wave partial tile
#pragma unroll
    for (int n = 0; n < 4; n++)
#pragma unroll
        for (int q = 0; q < 4; q++)
            accL[wv][4 * lhi + q][16 * n + l15] = acc[n][q];
    __syncthreads();

    if (t < 16) {
        float s4 = dnp[0][t] + dnp[1][t] + dnp[2][t] + dnp[3][t];
        dnr[t] = 1.0f / s4;
    }
    __syncthreads();

    // final reduce + normalize: thread t -> row r = t>>4, cols c4..c4+3
    int r = t >> 4;
    int c4 = (t & 15) * 4;
    float inv = dnr[r];
    float4 o;
    o.x = (accL[0][r][c4+0] + accL[1][r][c4+0] + accL[2][r][c4+0] + accL[3][r][c4+0]) * inv;
    o.y = (accL[0][r][c4+1] + accL[1][r][c4+1] + accL[2][r][c4+1] + accL[3][r][c4+1]) * inv;
    o.z = (accL[0][r][c4+2] + accL[1][r][c4+2] + accL[2][r][c4+2] + accL[3][r][c4+2]) * inv;
    o.w = (accL[0][r][c4+3] + accL[1][r][c4+3] + accL[2][r][c4+3] + accL[3][r][c4+3]) * inv;
    *(float4*)(pacc + (size_t)branch * 524288 + (size_t)(row0 + r) * 64 + c4) = o;
}

// ---------------- kernel 5: combine branches + ELU ----------------
__global__ __launch_bounds__(256) void k5_combine(const float* __restrict__ pacc,
                                                  float* __restrict__ out) {
    size_t idx = (size_t)blockIdx.x * 256 + threadIdx.x;   // float4 index
    float4 p0 = *(const float4*)(pacc + idx * 4);
    float4 p1 = *(const float4*)(pacc + 524288 + idx * 4);
    float4 o;
    float v;
    v = 0.5f * (p0.x + p1.x); o.x = (v > 0.f) ? v : (exp2f(v * L2E) - 1.f);
    v = 0.5f * (p0.y + p1.y); o.y = (v > 0.f) ? v : (exp2f(v * L2E) - 1.f);
    v = 0.5f * (p0.z + p1.z); o.z = (v > 0.f) ? v : (exp2f(v * L2E) - 1.f);
    v = 0.5f * (p0.w + p1.w); o.w = (v > 0.f) ? v : (exp2f(v * L2E) - 1.f);
    *(float4*)(out + idx * 4) = o;
}

extern "C" void kernel_launch(void* const* d_in, const int* in_sizes, int n_in,
                              void* d_out, int out_size, void* d_ws, size_t ws_size,
                              hipStream_t stream) {
    const float* x       = (const float*)d_in[0];
    const int*   adj_in  = (const int*)d_in[1];
    const int*   adj_out = (const int*)d_in[2];
    const float* W_in    = (const float*)d_in[3];
    const float* W_out   = (const float*)d_in[4];
    const float* a       = (const float*)d_in[5];
    float* out = (float*)d_out;

    char* ws = (char*)d_ws;
    f16*   WT   = (f16*)(ws + WS_WT);
    f16*   HT   = (f16*)(ws + WS_HT);
    float* srcw = (float*)(ws + WS_SRC);
    float* dstw = (float*)(ws + WS_DST);
    float* dmax = (float*)(ws + WS_DMAX);
    float* pacc = (float*)(ws + WS_PACC);
    // requires ws_size >= ~6.2 MB

    hipLaunchKernelGGL(k1_wt,     dim3(128),  dim3(256), 0, stream, W_in, W_out, WT);
    hipLaunchKernelGGL(k2_h,      dim3(512),  dim3(64),  0, stream, x, WT, a, HT, srcw, dstw);
    hipLaunchKernelGGL(k3_dmax,   dim3(1),    dim3(256), 0, stream, dstw, dmax);
    hipLaunchKernelGGL(k4_main,   dim3(1024), dim3(256), 0, stream, adj_in, adj_out, HT, srcw, dstw, dmax, pacc);
    hipLaunchKernelGGL(k5_combine,dim3(512),  dim3(256), 0, stream, pacc, out);
}

// Round 3
// 214.283 us; speedup vs baseline: 1.1390x; 1.1390x over previous
//
#include <hip/hip_runtime.h>
#include <hip/hip_bf16.h>
#include <stdint.h>

// GAT layer: N=8192, F_IN=256, F_OUT=64, two branches (adj_in/adj_out), shared 'a'.

#define NN 8192
#define ALPHA 0.2f
#define L2E 1.44269504088896f
#define AL2E 0.288539008177792f   // 0.2 * log2(e)

typedef _Float16 f16;
typedef _Float16 f16x2 __attribute__((ext_vector_type(2)));
typedef _Float16 f16x4 __attribute__((ext_vector_type(4)));
typedef _Float16 f16x8 __attribute__((ext_vector_type(8)));
typedef float f32x4 __attribute__((ext_vector_type(4)));
typedef unsigned int u32;

// workspace layout (bytes). E1/E2 overlay WT (k1/k2 finish with WT before k3b writes E).
#define WS_WT    0u         // f16 [128][256]  (transposed W_in|W_out)   -- dead after k2
#define WS_E1    0u         // f16 [2][8192]   exp2((d-dmax)*L2E)
#define WS_E2    32768u     // f16 [2][8192]   exp2(0.2*(d-dmax)*L2E)
#define WS_HT    65536u     // f16 [2][64][8192] (h transposed, per branch)
#define WS_SRC   2162688u   // f32 [2][8192]
#define WS_DST   2228224u   // f32 [2][8192]
#define WS_DMAX  2293760u   // f32 [2]
#define WS_PACC  2294016u   // f32 [2][8192][64]

static __device__ __forceinline__ void gload16(const void* g, void* l) {
    __builtin_amdgcn_global_load_lds(
        (const __attribute__((address_space(1))) void*)g,
        (__attribute__((address_space(3))) void*)l, 16, 0, 0);
}

// ---------------- kernel 1: WT[c][k] = W[k][c] as f16 ----------------
__global__ __launch_bounds__(256) void k1_wt(const float* __restrict__ Win,
                                             const float* __restrict__ Wout,
                                             f16* __restrict__ WT) {
    int c = blockIdx.x;          // 0..127 combined col
    int k = threadIdx.x;         // 0..255
    const float* W = (c < 64) ? Win : Wout;
    int cc = c & 63;
    WT[(size_t)c * 256 + k] = (f16)W[(size_t)k * 64 + cc];
}

// ---------------- kernel 2: h = x@W (MFMA), emit HT f16 + src/dst ----------------
__global__ __launch_bounds__(64) void k2_h(const float* __restrict__ x,
                                           const f16* __restrict__ WT,
                                           const float* __restrict__ a,
                                           f16* __restrict__ HT,
                                           float* __restrict__ srcw,
                                           float* __restrict__ dstw) {
    int l = threadIdx.x;
    int l15 = l & 15, lhi = l >> 4;
    int row0 = blockIdx.x * 16;

    f32x4 acc[8];
#pragma unroll
    for (int n = 0; n < 8; n++) { acc[n][0]=0.f; acc[n][1]=0.f; acc[n][2]=0.f; acc[n][3]=0.f; }

#pragma unroll
    for (int kc = 0; kc < 8; kc++) {
        int k = kc * 32 + lhi * 8;
        const float* xp = x + (size_t)(row0 + l15) * 256 + k;
        float4 xa = *(const float4*)xp;
        float4 xb = *(const float4*)(xp + 4);
        f16x8 af;
        af[0]=(f16)xa.x; af[1]=(f16)xa.y; af[2]=(f16)xa.z; af[3]=(f16)xa.w;
        af[4]=(f16)xb.x; af[5]=(f16)xb.y; af[6]=(f16)xb.z; af[7]=(f16)xb.w;
#pragma unroll
        for (int n = 0; n < 8; n++) {
            f16x8 bf = *(const f16x8*)(WT + (size_t)(16 * n + l15) * 256 + k);
            acc[n] = __builtin_amdgcn_mfma_f32_16x16x32_f16(af, bf, acc[n], 0, 0, 0);
        }
    }

    float as4[4], ad4[4];
#pragma unroll
    for (int nn = 0; nn < 4; nn++) {
        as4[nn] = a[16 * nn + l15];
        ad4[nn] = a[64 + 16 * nn + l15];
    }

    float s_in[4] = {0,0,0,0}, d_in[4] = {0,0,0,0};
    float s_out[4] = {0,0,0,0}, d_out[4] = {0,0,0,0};

#pragma unroll
    for (int n = 0; n < 8; n++) {
        int b = n >> 2;
        int ci = 16 * (n & 3) + l15;
        f16x4 hv;
#pragma unroll
        for (int q = 0; q < 4; q++) hv[q] = (f16)acc[n][q];
        *(f16x4*)(HT + (size_t)b * 524288 + (size_t)ci * 8192 + row0 + 4 * lhi) = hv;
#pragma unroll
        for (int q = 0; q < 4; q++) {
            float v = acc[n][q];
            if (b == 0) { s_in[q]  += v * as4[n & 3]; d_in[q]  += v * ad4[n & 3]; }
            else        { s_out[q] += v * as4[n & 3]; d_out[q] += v * ad4[n & 3]; }
        }
    }

#pragma unroll
    for (int q = 0; q < 4; q++) {
#pragma unroll
        for (int m = 1; m < 16; m <<= 1) {
            s_in[q]  += __shfl_xor(s_in[q],  m, 64);
            d_in[q]  += __shfl_xor(d_in[q],  m, 64);
            s_out[q] += __shfl_xor(s_out[q], m, 64);
            d_out[q] += __shfl_xor(d_out[q], m, 64);
        }
    }
    if (l15 == 0) {
        int row = row0 + 4 * lhi;
#pragma unroll
        for (int q = 0; q < 4; q++) {
            srcw[row + q]        = s_in[q];
            srcw[8192 + row + q] = s_out[q];
            dstw[row + q]        = d_in[q];
            dstw[8192 + row + q] = d_out[q];
        }
    }
}

// ---------------- kernel 3: per-branch max of dst ----------------
__global__ __launch_bounds__(256) void k3_dmax(const float* __restrict__ dstw,
                                               float* __restrict__ dmax) {
    __shared__ float red[2][4];
    int t = threadIdx.x;
    int l = t & 63, w = t >> 6;
    for (int b = 0; b < 2; b++) {
        float v = -1e30f;
        for (int i = t; i < 8192; i += 256) v = fmaxf(v, dstw[b * 8192 + i]);
#pragma unroll
        for (int m = 1; m < 64; m <<= 1) v = fmaxf(v, __shfl_xor(v, m, 64));
        if (l == 0) red[b][w] = v;
    }
    __syncthreads();
    if (t == 0) dmax[0] = fmaxf(fmaxf(red[0][0], red[0][1]), fmaxf(red[0][2], red[0][3]));
    if (t == 1) dmax[1] = fmaxf(fmaxf(red[1][0], red[1][1]), fmaxf(red[1][2], red[1][3]));
}

// ---------------- kernel 3b: E tables, f16, normalized by dmax ----------------
__global__ __launch_bounds__(256) void k3b_e(const float* __restrict__ dstw,
                                             const float* __restrict__ dmax,
                                             f16* __restrict__ E1,
                                             f16* __restrict__ E2) {
    int i = blockIdx.x * 256 + threadIdx.x;   // 0..16383
    int b = i >> 13;
    float d = dstw[i] - dmax[b];              // <= 0
    E1[i] = (f16)exp2f(d * L2E);
    E2[i] = (f16)exp2f(d * AL2E);
}

// ---------------- kernel 4: fused masked-softmax-attention ----------------
// Block = 4 waves, 16 rows, one branch. j tiled by 256; wave wv handles the
// 64-j subrange [tile*256 + wv*64, +64). adj tile [16][256 ints] staged into
// LDS via coalesced global_load_lds (1 row = 1 issue = 1KB), source
// XOR-swizzled per 16B-block so ds_read_b128 hits the structural bank minimum.
// One counted-vmcnt + s_barrier per tile (2-phase pipeline).
__global__ __launch_bounds__(256, 4) void k4_main(const int* __restrict__ adj_in,
                                                  const int* __restrict__ adj_out,
                                                  const f16* __restrict__ HT,
                                                  const float* __restrict__ srcw,
                                                  const float* __restrict__ dmaxp,
                                                  const f16* __restrict__ E1g,
                                                  const f16* __restrict__ E2g,
                                                  float* __restrict__ pacc) {
    __shared__ __align__(16) char lds[33024];   // [2][16][1024B] adj tiles; epilogue reuses

    int t = threadIdx.x;
    int branch = blockIdx.x & 1;
    int row0 = (blockIdx.x >> 1) * 16;
    const int* adj = (branch ? adj_out : adj_in) + (size_t)row0 * NN;
    const f16* htg = HT + (size_t)branch * (64 * NN);
    const f16* e1b = E1g + branch * NN;
    const f16* e2b = E2g + branch * NN;

    int l = t & 63, wv = t >> 6;
    int l15 = l & 15, lhi = l >> 4;
    int sw = l15 & 7;

    // per-row constants: ev = max(k1*E1[j], k2*E2[j]) = exp2(LR(src+d)*L2E - mlog)
    float srcv = srcw[branch * NN + row0 + l15];
    float dmaxv = dmaxp[branch];
    float md = srcv + dmaxv;
    float mlog = fmaxf(md, ALPHA * md) * L2E;
    f16 k1h = (f16)exp2f(md * L2E - mlog);          // <= 1
    f16 k2h = (f16)exp2f(ALPHA * md * L2E - mlog);  // <= 1
    f16x8 k1v, k2v;
#pragma unroll
    for (int i = 0; i < 8; i++) { k1v[i] = k1h; k2v[i] = k2h; }

    f32x4 acc[4];
#pragma unroll
    for (int n = 0; n < 4; n++) { acc[n][0]=0.f; acc[n][1]=0.f; acc[n][2]=0.f; acc[n][3]=0.f; }
    float dn = 0.f;
    f16x2 one2; one2[0] = (f16)1.f; one2[1] = (f16)1.f;

    auto stage = [&](int tile, int buf) {
        const int* base = adj + tile * 256;
#pragma unroll
        for (int i = 0; i < 4; i++) {
            int r = wv * 4 + i;
            const int* src = base + (size_t)r * NN + ((l ^ (r & 7)) << 2);
            gload16(src, lds + buf * 16384 + r * 1024);
        }
    };

    // prologue
    stage(0, 0);
    asm volatile("s_waitcnt vmcnt(0)" ::: "memory");
    __builtin_amdgcn_s_barrier();

    for (int tile = 0; tile < 32; tile++) {
        int buf = tile & 1;
        if (tile < 31) stage(tile + 1, buf ^ 1);

#pragma unroll
        for (int ss = 0; ss < 2; ss++) {
            int jloc = wv * 64 + ss * 32;
            int qb = (jloc >> 2) + 2 * lhi;
            const char* rowp = lds + buf * 16384 + l15 * 1024;
            int4 a0 = *(const int4*)(rowp + (((qb    ) ^ sw) << 4));
            int4 a1 = *(const int4*)(rowp + (((qb + 1) ^ sw) << 4));

            int jg = tile * 256 + jloc + lhi * 8;
            f16x8 e1v = *(const f16x8*)(e1b + jg);
            f16x8 e2v = *(const f16x8*)(e2b + jg);
            f16x8 w = __builtin_elementwise_max(e1v * k1v, e2v * k2v);

            // mask: adj in {0,1} -> packed f16 {0,1} pairs via (a0|a1<<16)*0x3C00
            union { u32 u[4]; f16x8 h; } mu;
            mu.u[0] = (u32)(a0.x + (a0.y << 16)) * 0x3C00u;
            mu.u[1] = (u32)(a0.z + (a0.w << 16)) * 0x3C00u;
            mu.u[2] = (u32)(a1.x + (a1.y << 16)) * 0x3C00u;
            mu.u[3] = (u32)(a1.z + (a1.w << 16)) * 0x3C00u;
            w = w * mu.h;

            union { f16x8 h; f16x2 p[4]; } wu; wu.h = w;
#if __has_builtin(__builtin_amdgcn_fdot2)
            dn = __builtin_amdgcn_fdot2(wu.p[0], one2, dn, false);
            dn = __builtin_amdgcn_fdot2(wu.p[1], one2, dn, false);
            dn = __builtin_amdgcn_fdot2(wu.p[2], one2, dn, false);
            dn = __builtin_amdgcn_fdot2(wu.p[3], one2, dn, false);
#else
#pragma unroll
            for (int e = 0; e < 8; e++) dn += (float)w[e];
#endif

            const f16* hb = htg + (size_t)l15 * NN + jg;
            f16x8 b0 = *(const f16x8*)(hb);
            f16x8 b1 = *(const f16x8*)(hb + 16 * NN);
            f16x8 b2 = *(const f16x8*)(hb + 32 * NN);
            f16x8 b3 = *(const f16x8*)(hb + 48 * NN);
            acc[0] = __builtin_amdgcn_mfma_f32_16x16x32_f16(w, b0, acc[0], 0, 0, 0);
            acc[1] = __builtin_amdgcn_mfma_f32_16x16x32_f16(w, b1, acc[1], 0, 0, 0);
            acc[2] = __builtin_amdgcn_mfma_f32_16x16x32_f16(w, b2, acc[2], 0, 0, 0);
            acc[3] = __builtin_amdgcn_mfma_f32_16x16x32_f16(w, b3, acc[3], 0, 0, 0);
        }

        asm volatile("s_waitcnt vmcnt(0)" ::: "memory");
        __builtin_amdgcn_s_barrier();
    }

    // epilogue: reduce dn across lhi groups, merge 4 waves' partials in LDS
    dn += __shfl_xor(dn, 16, 64);
    dn += __shfl_xor(dn, 32, 64);

    float* accL = (float*)lds;               // [4][16][64]
    float* dnp  = (float*)(lds + 16384);     // [4][16]
    float* dnr  = (float*)(lds + 16384 + 256);
    if (lhi == 0) dnp[wv * 16 + l15] = dn;
#pragma unroll
    for (int n = 0; n < 4; n++)
#pragma unroll
        for (int q = 0; q < 4; q++)
            accL[wv * 1024 + (4 * lhi + q) * 64 + 16 * n + l15] = acc[n][q];
    __syncthreads();

    if (t < 16) dnr[t] = 1.0f / (dnp[t] + dnp[16 + t] + dnp[32 + t] + dnp[48 + t]);
    __syncthreads();

    int r = t >> 4;
    int c4 = (t & 15) * 4;
    float inv = dnr[r];
    float4 o;
    o.x = (accL[r*64+c4+0] + accL[1024+r*64+c4+0] + accL[2048+r*64+c4+0] + accL[3072+r*64+c4+0]) * inv;
    o.y = (accL[r*64+c4+1] + accL[1024+r*64+c4+1] + accL[2048+r*64+c4+1] + accL[3072+r*64+c4+1]) * inv;
    o.z = (accL[r*64+c4+2] + accL[1024+r*64+c4+2] + accL[2048+r*64+c4+2] + accL[3072+r*64+c4+2]) * inv;
    o.w = (accL[r*64+c4+3] + accL[1024+r*64+c4+3] + accL[2048+r*64+c4+3] + accL[3072+r*64+c4+3]) * inv;
    *(float4*)(pacc + (size_t)branch * 524288 + (size_t)(row0 + r) * 64 + c4) = o;
}

// ---------------- kernel 5: combine branches + ELU ----------------
__global__ __launch_bounds__(256) void k5_combine(const float* __restrict__ pacc,
                                                  float* __restrict__ out) {
    size_t idx = (size_t)blockIdx.x * 256 + threadIdx.x;   // float4 index
    float4 p0 = *(const float4*)(pacc + idx * 4);
    float4 p1 = *(const float4*)(pacc + 524288 + idx * 4);
    float4 o;
    float v;
    v = 0.5f * (p0.x + p1.x); o.x = (v > 0.f) ? v : (exp2f(v * L2E) - 1.f);
    v = 0.5f * (p0.y + p1.y); o.y = (v > 0.f) ? v : (exp2f(v * L2E) - 1.f);
    v = 0.5f * (p0.z + p1.z); o.z = (v > 0.f) ? v : (exp2f(v * L2E) - 1.f);
    v = 0.5f * (p0.w + p1.w); o.w = (v > 0.f) ? v : (exp2f(v * L2E) - 1.f);
    *(float4*)(out + idx * 4) = o;
}

extern "C" void kernel_launch(void* const* d_in, const int* in_sizes, int n_in,
                              void* d_out, int out_size, void* d_ws, size_t ws_size,
                              hipStream_t stream) {
    const float* x       = (const float*)d_in[0];
    const int*   adj_in  = (const int*)d_in[1];
    const int*   adj_out = (const int*)d_in[2];
    const float* W_in    = (const float*)d_in[3];
    const float* W_out   = (const float*)d_in[4];
    const float* a       = (const float*)d_in[5];
    float* out = (float*)d_out;

    char* ws = (char*)d_ws;
    f16*   WT   = (f16*)(ws + WS_WT);
    f16*   E1   = (f16*)(ws + WS_E1);    // overlays WT (dead after k2)
    f16*   E2   = (f16*)(ws + WS_E2);
    f16*   HT   = (f16*)(ws + WS_HT);
    float* srcw = (float*)(ws + WS_SRC);
    float* dstw = (float*)(ws + WS_DST);
    float* dmax = (float*)(ws + WS_DMAX);
    float* pacc = (float*)(ws + WS_PACC);
    // requires ws_size >= ~6.2 MB (same footprint as previous round)

    hipLaunchKernelGGL(k1_wt,     dim3(128),  dim3(256), 0, stream, W_in, W_out, WT);
    hipLaunchKernelGGL(k2_h,      dim3(512),  dim3(64),  0, stream, x, WT, a, HT, srcw, dstw);
    hipLaunchKernelGGL(k3_dmax,   dim3(1),    dim3(256), 0, stream, dstw, dmax);
    hipLaunchKernelGGL(k3b_e,     dim3(64),   dim3(256), 0, stream, dstw, dmax, E1, E2);
    hipLaunchKernelGGL(k4_main,   dim3(1024), dim3(256), 0, stream, adj_in, adj_out, HT, srcw, dmax, E1, E2, pacc);
    hipLaunchKernelGGL(k5_combine,dim3(512),  dim3(256), 0, stream, pacc, out);
}

// Round 4
// 160.695 us; speedup vs baseline: 1.5188x; 1.3335x over previous
//
#include <hip/hip_runtime.h>
#include <hip/hip_bf16.h>
#include <stdint.h>

// GAT layer: N=8192, F_IN=256, F_OUT=64, two branches (adj_in/adj_out), shared 'a'.

#define NN 8192
#define ALPHA 0.2f
#define L2E 1.44269504088896f
#define AL2E 0.288539008177792f   // 0.2 * log2(e)

typedef _Float16 f16;
typedef _Float16 f16x2 __attribute__((ext_vector_type(2)));
typedef _Float16 f16x4 __attribute__((ext_vector_type(4)));
typedef _Float16 f16x8 __attribute__((ext_vector_type(8)));
typedef float f32x4 __attribute__((ext_vector_type(4)));
typedef unsigned int u32;

// workspace layout (bytes). E1/E2 overlay WT (k1/k2 finish with WT before k3b writes E).
#define WS_WT    0u         // f16 [128][256]  (transposed W_in|W_out)   -- dead after k2
#define WS_E1    0u         // f16 [2][8192]   exp2((d-dmax)*L2E)
#define WS_E2    32768u     // f16 [2][8192]   exp2(0.2*(d-dmax)*L2E)
#define WS_HT    65536u     // f16 [2][1024][64][8] blocked: HTB[b][j>>3][c][j&7]
#define WS_SRC   2162688u   // f32 [2][8192]
#define WS_DST   2228224u   // f32 [2][8192]
#define WS_DMAX  2293760u   // f32 [2]
#define WS_PACC  2294016u   // f32 [2][8192][64]

static __device__ __forceinline__ void gload16(const void* g, void* l) {
    __builtin_amdgcn_global_load_lds(
        (const __attribute__((address_space(1))) void*)g,
        (__attribute__((address_space(3))) void*)l, 16, 0, 0);
}

// ---------------- kernel 1: WT[c][k] = W[k][c] as f16 ----------------
__global__ __launch_bounds__(256) void k1_wt(const float* __restrict__ Win,
                                             const float* __restrict__ Wout,
                                             f16* __restrict__ WT) {
    int c = blockIdx.x;          // 0..127 combined col
    int k = threadIdx.x;         // 0..255
    const float* W = (c < 64) ? Win : Wout;
    int cc = c & 63;
    WT[(size_t)c * 256 + k] = (f16)W[(size_t)k * 64 + cc];
}

// ---------------- kernel 2: h = x@W (MFMA), emit blocked HTB f16 + src/dst ----------------
__global__ __launch_bounds__(64) void k2_h(const float* __restrict__ x,
                                           const f16* __restrict__ WT,
                                           const float* __restrict__ a,
                                           f16* __restrict__ HT,
                                           float* __restrict__ srcw,
                                           float* __restrict__ dstw) {
    int l = threadIdx.x;
    int l15 = l & 15, lhi = l >> 4;
    int row0 = blockIdx.x * 16;

    f32x4 acc[8];
#pragma unroll
    for (int n = 0; n < 8; n++) { acc[n][0]=0.f; acc[n][1]=0.f; acc[n][2]=0.f; acc[n][3]=0.f; }

#pragma unroll
    for (int kc = 0; kc < 8; kc++) {
        int k = kc * 32 + lhi * 8;
        const float* xp = x + (size_t)(row0 + l15) * 256 + k;
        float4 xa = *(const float4*)xp;
        float4 xb = *(const float4*)(xp + 4);
        f16x8 af;
        af[0]=(f16)xa.x; af[1]=(f16)xa.y; af[2]=(f16)xa.z; af[3]=(f16)xa.w;
        af[4]=(f16)xb.x; af[5]=(f16)xb.y; af[6]=(f16)xb.z; af[7]=(f16)xb.w;
#pragma unroll
        for (int n = 0; n < 8; n++) {
            f16x8 bf = *(const f16x8*)(WT + (size_t)(16 * n + l15) * 256 + k);
            acc[n] = __builtin_amdgcn_mfma_f32_16x16x32_f16(af, bf, acc[n], 0, 0, 0);
        }
    }

    float as4[4], ad4[4];
#pragma unroll
    for (int nn = 0; nn < 4; nn++) {
        as4[nn] = a[16 * nn + l15];
        ad4[nn] = a[64 + 16 * nn + l15];
    }

    float s_in[4] = {0,0,0,0}, d_in[4] = {0,0,0,0};
    float s_out[4] = {0,0,0,0}, d_out[4] = {0,0,0,0};

#pragma unroll
    for (int n = 0; n < 8; n++) {
        int b = n >> 2;
        int ci = 16 * (n & 3) + l15;
        int jj = row0 + 4 * lhi;     // j position of this f16x4
        f16x4 hv;
#pragma unroll
        for (int q = 0; q < 4; q++) hv[q] = (f16)acc[n][q];
        // blocked layout: HTB[b][jj>>3][ci][jj&7]
        *(f16x4*)(HT + (size_t)b * 524288 + (size_t)(jj >> 3) * 512 + (size_t)ci * 8 + (jj & 7)) = hv;
#pragma unroll
        for (int q = 0; q < 4; q++) {
            float v = acc[n][q];
            if (b == 0) { s_in[q]  += v * as4[n & 3]; d_in[q]  += v * ad4[n & 3]; }
            else        { s_out[q] += v * as4[n & 3]; d_out[q] += v * ad4[n & 3]; }
        }
    }

#pragma unroll
    for (int q = 0; q < 4; q++) {
#pragma unroll
        for (int m = 1; m < 16; m <<= 1) {
            s_in[q]  += __shfl_xor(s_in[q],  m, 64);
            d_in[q]  += __shfl_xor(d_in[q],  m, 64);
            s_out[q] += __shfl_xor(s_out[q], m, 64);
            d_out[q] += __shfl_xor(d_out[q], m, 64);
        }
    }
    if (l15 == 0) {
        int row = row0 + 4 * lhi;
#pragma unroll
        for (int q = 0; q < 4; q++) {
            srcw[row + q]        = s_in[q];
            srcw[8192 + row + q] = s_out[q];
            dstw[row + q]        = d_in[q];
            dstw[8192 + row + q] = d_out[q];
        }
    }
}

// ---------------- kernel 3: per-branch max of dst ----------------
__global__ __launch_bounds__(256) void k3_dmax(const float* __restrict__ dstw,
                                               float* __restrict__ dmax) {
    __shared__ float red[2][4];
    int t = threadIdx.x;
    int l = t & 63, w = t >> 6;
    for (int b = 0; b < 2; b++) {
        float v = -1e30f;
        for (int i = t; i < 8192; i += 256) v = fmaxf(v, dstw[b * 8192 + i]);
#pragma unroll
        for (int m = 1; m < 64; m <<= 1) v = fmaxf(v, __shfl_xor(v, m, 64));
        if (l == 0) red[b][w] = v;
    }
    __syncthreads();
    if (t == 0) dmax[0] = fmaxf(fmaxf(red[0][0], red[0][1]), fmaxf(red[0][2], red[0][3]));
    if (t == 1) dmax[1] = fmaxf(fmaxf(red[1][0], red[1][1]), fmaxf(red[1][2], red[1][3]));
}

// ---------------- kernel 3b: E tables, f16, normalized by dmax ----------------
__global__ __launch_bounds__(256) void k3b_e(const float* __restrict__ dstw,
                                             const float* __restrict__ dmax,
                                             f16* __restrict__ E1,
                                             f16* __restrict__ E2) {
    int i = blockIdx.x * 256 + threadIdx.x;   // 0..16383
    int b = i >> 13;
    float d = dstw[i] - dmax[b];              // <= 0
    E1[i] = (f16)exp2f(d * L2E);
    E2[i] = (f16)exp2f(d * AL2E);
}

// ---------------- kernel 4: fused masked-softmax-attention ----------------
// Identical structure to round 3 (adj via coalesced global_load_lds, 2-phase
// counted pipeline, one vmcnt(0)+barrier per 256-j tile). Single change:
// HT is read in the blocked layout HTB[j>>3][c][j&7], so each B-fragment load
// is 4x 256B dense chunks (vs 16x sparse 64B) -> ~4x fewer L2 transactions.
__global__ __launch_bounds__(256, 4) void k4_main(const int* __restrict__ adj_in,
                                                  const int* __restrict__ adj_out,
                                                  const f16* __restrict__ HT,
                                                  const float* __restrict__ srcw,
                                                  const float* __restrict__ dmaxp,
                                                  const f16* __restrict__ E1g,
                                                  const f16* __restrict__ E2g,
                                                  float* __restrict__ pacc) {
    __shared__ __align__(16) char lds[33024];   // [2][16][1024B] adj tiles; epilogue reuses

    int t = threadIdx.x;
    int branch = blockIdx.x & 1;
    int row0 = (blockIdx.x >> 1) * 16;
    const int* adj = (branch ? adj_out : adj_in) + (size_t)row0 * NN;
    const f16* htg = HT + (size_t)branch * (64 * NN);
    const f16* e1b = E1g + branch * NN;
    const f16* e2b = E2g + branch * NN;

    int l = t & 63, wv = t >> 6;
    int l15 = l & 15, lhi = l >> 4;
    int sw = l15 & 7;

    // per-row constants: ev = max(k1*E1[j], k2*E2[j]) = exp2(LR(src+d)*L2E - mlog)
    float srcv = srcw[branch * NN + row0 + l15];
    float dmaxv = dmaxp[branch];
    float md = srcv + dmaxv;
    float mlog = fmaxf(md, ALPHA * md) * L2E;
    f16 k1h = (f16)exp2f(md * L2E - mlog);          // <= 1
    f16 k2h = (f16)exp2f(ALPHA * md * L2E - mlog);  // <= 1
    f16x8 k1v, k2v;
#pragma unroll
    for (int i = 0; i < 8; i++) { k1v[i] = k1h; k2v[i] = k2h; }

    f32x4 acc[4];
#pragma unroll
    for (int n = 0; n < 4; n++) { acc[n][0]=0.f; acc[n][1]=0.f; acc[n][2]=0.f; acc[n][3]=0.f; }
    float dn = 0.f;
    f16x2 one2; one2[0] = (f16)1.f; one2[1] = (f16)1.f;

    auto stage = [&](int tile, int buf) {
        const int* base = adj + tile * 256;
#pragma unroll
        for (int i = 0; i < 4; i++) {
            int r = wv * 4 + i;
            const int* src = base + (size_t)r * NN + ((l ^ (r & 7)) << 2);
            gload16(src, lds + buf * 16384 + r * 1024);
        }
    };

    // prologue
    stage(0, 0);
    asm volatile("s_waitcnt vmcnt(0)" ::: "memory");
    __builtin_amdgcn_s_barrier();

    for (int tile = 0; tile < 32; tile++) {
        int buf = tile & 1;
        if (tile < 31) stage(tile + 1, buf ^ 1);

#pragma unroll
        for (int ss = 0; ss < 2; ss++) {
            int jloc = wv * 64 + ss * 32;
            int qb = (jloc >> 2) + 2 * lhi;
            const char* rowp = lds + buf * 16384 + l15 * 1024;
            int4 a0 = *(const int4*)(rowp + (((qb    ) ^ sw) << 4));
            int4 a1 = *(const int4*)(rowp + (((qb + 1) ^ sw) << 4));

            int jg = tile * 256 + jloc + lhi * 8;
            f16x8 e1v = *(const f16x8*)(e1b + jg);
            f16x8 e2v = *(const f16x8*)(e2b + jg);
            f16x8 w = __builtin_elementwise_max(e1v * k1v, e2v * k2v);

            // mask: adj in {0,1} -> packed f16 {0,1} pairs via (a0|a1<<16)*0x3C00
            union { u32 u[4]; f16x8 h; } mu;
            mu.u[0] = (u32)(a0.x + (a0.y << 16)) * 0x3C00u;
            mu.u[1] = (u32)(a0.z + (a0.w << 16)) * 0x3C00u;
            mu.u[2] = (u32)(a1.x + (a1.y << 16)) * 0x3C00u;
            mu.u[3] = (u32)(a1.z + (a1.w << 16)) * 0x3C00u;
            w = w * mu.h;

            union { f16x8 h; f16x2 p[4]; } wu; wu.h = w;
#if __has_builtin(__builtin_amdgcn_fdot2)
            dn = __builtin_amdgcn_fdot2(wu.p[0], one2, dn, false);
            dn = __builtin_amdgcn_fdot2(wu.p[1], one2, dn, false);
            dn = __builtin_amdgcn_fdot2(wu.p[2], one2, dn, false);
            dn = __builtin_amdgcn_fdot2(wu.p[3], one2, dn, false);
#else
#pragma unroll
            for (int e = 0; e < 8; e++) dn += (float)w[e];
#endif

            // blocked HT read: blk = jg>>3, fragment cols c = 16n + l15
            const f16* hb = htg + (size_t)(jg >> 3) * 512 + l15 * 8;
            f16x8 b0 = *(const f16x8*)(hb);
            f16x8 b1 = *(const f16x8*)(hb + 128);
            f16x8 b2 = *(const f16x8*)(hb + 256);
            f16x8 b3 = *(const f16x8*)(hb + 384);
            acc[0] = __builtin_amdgcn_mfma_f32_16x16x32_f16(w, b0, acc[0], 0, 0, 0);
            acc[1] = __builtin_amdgcn_mfma_f32_16x16x32_f16(w, b1, acc[1], 0, 0, 0);
            acc[2] = __builtin_amdgcn_mfma_f32_16x16x32_f16(w, b2, acc[2], 0, 0, 0);
            acc[3] = __builtin_amdgcn_mfma_f32_16x16x32_f16(w, b3, acc[3], 0, 0, 0);
        }

        asm volatile("s_waitcnt vmcnt(0)" ::: "memory");
        __builtin_amdgcn_s_barrier();
    }

    // epilogue: reduce dn across lhi groups, merge 4 waves' partials in LDS
    dn += __shfl_xor(dn, 16, 64);
    dn += __shfl_xor(dn, 32, 64);

    float* accL = (float*)lds;               // [4][16][64]
    float* dnp  = (float*)(lds + 16384);     // [4][16]
    float* dnr  = (float*)(lds + 16384 + 256);
    if (lhi == 0) dnp[wv * 16 + l15] = dn;
#pragma unroll
    for (int n = 0; n < 4; n++)
#pragma unroll
        for (int q = 0; q < 4; q++)
            accL[wv * 1024 + (4 * lhi + q) * 64 + 16 * n + l15] = acc[n][q];
    __syncthreads();

    if (t < 16) dnr[t] = 1.0f / (dnp[t] + dnp[16 + t] + dnp[32 + t] + dnp[48 + t]);
    __syncthreads();

    int r = t >> 4;
    int c4 = (t & 15) * 4;
    float inv = dnr[r];
    float4 o;
    o.x = (accL[r*64+c4+0] + accL[1024+r*64+c4+0] + accL[2048+r*64+c4+0] + accL[3072+r*64+c4+0]) * inv;
    o.y = (accL[r*64+c4+1] + accL[1024+r*64+c4+1] + accL[2048+r*64+c4+1] + accL[3072+r*64+c4+1]) * inv;
    o.z = (accL[r*64+c4+2] + accL[1024+r*64+c4+2] + accL[2048+r*64+c4+2] + accL[3072+r*64+c4+2]) * inv;
    o.w = (accL[r*64+c4+3] + accL[1024+r*64+c4+3] + accL[2048+r*64+c4+3] + accL[3072+r*64+c4+3]) * inv;
    *(float4*)(pacc + (size_t)branch * 524288 + (size_t)(row0 + r) * 64 + c4) = o;
}

// ---------------- kernel 5: combine branches + ELU ----------------
__global__ __launch_bounds__(256) void k5_combine(const float* __restrict__ pacc,
                                                  float* __restrict__ out) {
    size_t idx = (size_t)blockIdx.x * 256 + threadIdx.x;   // float4 index
    float4 p0 = *(const float4*)(pacc + idx * 4);
    float4 p1 = *(const float4*)(pacc + 524288 + idx * 4);
    float4 o;
    float v;
    v = 0.5f * (p0.x + p1.x); o.x = (v > 0.f) ? v : (exp2f(v * L2E) - 1.f);
    v = 0.5f * (p0.y + p1.y); o.y = (v > 0.f) ? v : (exp2f(v * L2E) - 1.f);
    v = 0.5f * (p0.z + p1.z); o.z = (v > 0.f) ? v : (exp2f(v * L2E) - 1.f);
    v = 0.5f * (p0.w + p1.w); o.w = (v > 0.f) ? v : (exp2f(v * L2E) - 1.f);
    *(float4*)(out + idx * 4) = o;
}

extern "C" void kernel_launch(void* const* d_in, const int* in_sizes, int n_in,
                              void* d_out, int out_size, void* d_ws, size_t ws_size,
                              hipStream_t stream) {
    const float* x       = (const float*)d_in[0];
    const int*   adj_in  = (const int*)d_in[1];
    const int*   adj_out = (const int*)d_in[2];
    const float* W_in    = (const float*)d_in[3];
    const float* W_out   = (const float*)d_in[4];
    const float* a       = (const float*)d_in[5];
    float* out = (float*)d_out;

    char* ws = (char*)d_ws;
    f16*   WT   = (f16*)(ws + WS_WT);
    f16*   E1   = (f16*)(ws + WS_E1);    // overlays WT (dead after k2)
    f16*   E2   = (f16*)(ws + WS_E2);
    f16*   HT   = (f16*)(ws + WS_HT);
    float* srcw = (float*)(ws + WS_SRC);
    float* dstw = (float*)(ws + WS_DST);
    float* dmax = (float*)(ws + WS_DMAX);
    float* pacc = (float*)(ws + WS_PACC);
    // requires ws_size >= ~6.2 MB (same footprint as previous round)

    hipLaunchKernelGGL(k1_wt,     dim3(128),  dim3(256), 0, stream, W_in, W_out, WT);
    hipLaunchKernelGGL(k2_h,      dim3(512),  dim3(64),  0, stream, x, WT, a, HT, srcw, dstw);
    hipLaunchKernelGGL(k3_dmax,   dim3(1),    dim3(256), 0, stream, dstw, dmax);
    hipLaunchKernelGGL(k3b_e,     dim3(64),   dim3(256), 0, stream, dstw, dmax, E1, E2);
    hipLaunchKernelGGL(k4_main,   dim3(1024), dim3(256), 0, stream, adj_in, adj_out, HT, srcw, dmax, E1, E2, pacc);
    hipLaunchKernelGGL(k5_combine,dim3(512),  dim3(256), 0, stream, pacc, out);
}